// Round 12
// baseline (311.022 us; speedup 1.0000x reference)
//
#include <hip/hip_runtime.h>

#define NN 100000     // nodes
#define NE 1600000    // edges
#define FIN 100
#define D 64
#define NCONV 4
#define NG 500

// ---- bucket-sort CSR build params ----
#define NB 196                          // coarse buckets (col >> 9)
#define BSH 9
#define EPB 4096                        // edges per block in hist/scatter
#define NBLKA ((NE + EPB - 1) / EPB)    // 391
#define NSCAN (NB * NBLKA)              // 76636
#define SB 512                          // scan / bcsr block size
#define NBLKS ((NSCAN + SB - 1) / SB)   // 150

#define LSTR 136                        // LDS row stride (bf16) for lin0 staging
#define ASTR 72                         // LDS row stride (ushort) for fused conv tile

typedef unsigned int uint;
typedef unsigned short ushort;
typedef __attribute__((ext_vector_type(8))) short bf16x8;
typedef __attribute__((ext_vector_type(4))) float f32x4;

// f32 -> bf16 round-to-nearest-even
__device__ inline ushort f2bf(float x) {
    uint u = __float_as_uint(x);
    u += 0x7fffu + ((u >> 16) & 1u);
    return (ushort)(u >> 16);
}
__device__ inline float bflo(uint u) { return __uint_as_float(u << 16); }
__device__ inline float bfhi(uint u) { return __uint_as_float(u & 0xffff0000u); }
__device__ inline float bf2f(ushort s) { return __uint_as_float((uint)s << 16); }

// ---------------- pass A1: per-block LDS histogram over 196 buckets ----------
__global__ __launch_bounds__(256) void k_hist(const int* __restrict__ col,
                                              int* __restrict__ ghist) {
    __shared__ int lh[NB];
    int t = threadIdx.x;
    if (t < NB) lh[t] = 0;
    __syncthreads();
    int base = blockIdx.x * EPB;
    #pragma unroll
    for (int i = 0; i < 16; ++i) {
        int e = base + i * 256 + t;
        if (e < NE) atomicAdd(&lh[col[e] >> BSH], 1);
    }
    __syncthreads();
    if (t < NB) ghist[t * NBLKA + blockIdx.x] = lh[t];
}

// ---------------- generic two-level exclusive scan ----------------
__global__ __launch_bounds__(SB) void s_scan1(const int* __restrict__ in,
                                              int* __restrict__ out,
                                              int* __restrict__ bsums, int n) {
    __shared__ int sh[SB];
    int t = threadIdx.x, i = blockIdx.x * SB + t;
    int v = (i < n) ? in[i] : 0;
    sh[t] = v;
    __syncthreads();
    for (int off = 1; off < SB; off <<= 1) {
        int u = (t >= off) ? sh[t - off] : 0;
        __syncthreads();
        sh[t] += u;
        __syncthreads();
    }
    if (i < n) out[i] = sh[t] - v;
    if (t == SB - 1) bsums[blockIdx.x] = sh[t];
}

__global__ __launch_bounds__(SB) void s_scan2(int* __restrict__ bsums, int nb) {
    __shared__ int sh[SB];
    int t = threadIdx.x;
    int v = (t < nb) ? bsums[t] : 0;
    sh[t] = v;
    __syncthreads();
    for (int off = 1; off < SB; off <<= 1) {
        int u = (t >= off) ? sh[t - off] : 0;
        __syncthreads();
        sh[t] += u;
        __syncthreads();
    }
    if (t < nb) bsums[t] = sh[t] - v;
}

__global__ __launch_bounds__(SB) void s_scan3(int* __restrict__ out,
                                              const int* __restrict__ bsums, int n) {
    int i = blockIdx.x * SB + threadIdx.x;
    if (i < n) out[i] += bsums[blockIdx.x];
}

// ---------------- pass A3: scatter edges into bucket-sorted order -------------
__global__ __launch_bounds__(256) void k_scatter(const int* __restrict__ row,
                                                 const int* __restrict__ col,
                                                 const float* __restrict__ ew,
                                                 const int* __restrict__ gscan,
                                                 int2* __restrict__ sorted) {
    __shared__ int lcur[NB];
    int t = threadIdx.x;
    if (t < NB) lcur[t] = gscan[t * NBLKA + blockIdx.x];
    __syncthreads();
    int base = blockIdx.x * EPB;
    #pragma unroll
    for (int i = 0; i < 16; ++i) {
        int e = base + i * 256 + t;
        if (e < NE) {
            int c = col[e];
            int pos = atomicAdd(&lcur[c >> BSH], 1);
            sorted[pos] = make_int2(row[e] | ((c & 511) << 17), __float_as_int(ew[e]));
        }
    }
}

// ---------------- pass B: per-bucket fine CSR + degree (fused) ----------------
__global__ __launch_bounds__(SB) void k_bcsr(const int2* __restrict__ sorted,
                                             const int* __restrict__ gscan,
                                             int* __restrict__ rowstart,
                                             int2* __restrict__ csr,
                                             float* __restrict__ dis) {
    __shared__ int lcnt[SB];
    __shared__ int lscan[SB];
    __shared__ float ldeg[SB];
    int t = threadIdx.x, b = blockIdx.x;
    int base = gscan[b * NBLKA];
    int end  = (b == NB - 1) ? NE : gscan[(b + 1) * NBLKA];
    lcnt[t] = 0;
    ldeg[t] = 0.f;
    __syncthreads();
    for (int e = base + t; e < end; e += SB) {
        int2 p = sorted[e];
        int c = p.x >> 17;
        atomicAdd(&lcnt[c], 1);
        atomicAdd(&ldeg[c], __int_as_float(p.y));
    }
    __syncthreads();
    int v = lcnt[t];
    lscan[t] = v;
    __syncthreads();
    for (int off = 1; off < SB; off <<= 1) {
        int u = (t >= off) ? lscan[t - off] : 0;
        __syncthreads();
        lscan[t] += u;
        __syncthreads();
    }
    int ex = lscan[t] - v;           // exclusive scan within bucket
    int idx = b * SB + t;
    if (idx <= NN) rowstart[idx] = base + ex;
    if (idx < NN) {
        float dd = ldeg[t];
        dis[idx] = (dd > 0.f) ? (1.0f / sqrtf(dd)) : 0.f;
    }
    lcnt[t] = base + ex;             // cursor
    __syncthreads();
    for (int e = base + t; e < end; e += SB) {
        int2 p = sorted[e];
        int slot = atomicAdd(&lcnt[p.x >> 17], 1);
        csr[slot] = make_int2(p.x & 0x1FFFF, p.y);
    }
}

// ---------------- csr weight: ew -> dis[src]*ew*dis[dst], coalesced -----------
__global__ __launch_bounds__(256) void k_rownorm(int2* __restrict__ csr,
                                                 const int* __restrict__ rowstart,
                                                 const float* __restrict__ dis) {
    int t = threadIdx.x;
    int node = blockIdx.x * 16 + (t >> 4);
    int f = t & 15;
    int e0 = rowstart[node], e1 = rowstart[node + 1];
    float dc = dis[node];
    for (int e = e0 + f; e < e1; e += 16) {
        int2 p = csr[e];
        float w = dis[p.x] * __int_as_float(p.y) * dc;
        csr[e] = make_int2(p.x, __float_as_int(w));
    }
}

// ---------------- fused weight split (conv layers + lin0), pre-swizzled -------
// conv frag layout: [layer][ct:4][kh:2][h:2][lane:64][j:8] bf16
// lin0 frag layout: [ct:4][ks:4][h:2][lane:64][j:8], K zero-padded 100->128
__global__ void k_wsplit_all(const float* __restrict__ conv_w,
                             const float* __restrict__ lin0_w,
                             ushort* __restrict__ wf, ushort* __restrict__ wf0) {
    int tid = blockIdx.x * blockDim.x + threadIdx.x;   // 16384 + 8192 = 24576
    if (tid < 16384) {
        int j = tid & 7;
        int lane = (tid >> 3) & 63;
        int kh = (tid >> 9) & 1;
        int ct = (tid >> 10) & 3;
        int l = tid >> 12;
        int k = kh * 32 + (lane >> 4) * 8 + j;
        int n = ct * 16 + (lane & 15);
        float w = conv_w[l * D * D + k * D + n];
        ushort hi = f2bf(w);
        ushort lo = f2bf(w - bf2f(hi));
        int base = (((l * 4 + ct) * 2 + kh) * 2) * 512 + lane * 8 + j;
        wf[base] = hi;
        wf[base + 512] = lo;
    } else {
        int s = tid - 16384;
        int j = s & 7;
        int lane = (s >> 3) & 63;
        int ks = (s >> 9) & 3;
        int ct = s >> 11;
        int k = ks * 32 + (lane >> 4) * 8 + j;
        int n = ct * 16 + (lane & 15);
        float v = (k < FIN) ? lin0_w[k * D + n] : 0.f;
        ushort hi = f2bf(v);
        ushort lo = f2bf(v - bf2f(hi));
        int base = ((ct * 4 + ks) * 2) * 512 + lane * 8 + j;
        wf0[base] = hi;
        wf0[base + 512] = lo;
    }
}

// ---------------- lin0 via MFMA: out = relu(xhi @ (Whi+Wlo) + b0) -> bf16 -----
__global__ __launch_bounds__(256) void k_lin0_mfma(const float* __restrict__ x,
                                                   const ushort* __restrict__ wf,
                                                   const float* __restrict__ b,
                                                   ushort* __restrict__ out) {
    __shared__ ushort xhi[64 * LSTR];   // 17.4 KB
    int t = threadIdx.x;
    int r0 = blockIdx.x * 64;
    for (int i = t; i < 1600; i += 256) {           // 64 rows x 25 float4
        int r = i / 25, c4 = i - (i / 25) * 25;
        float4 v = {0.f, 0.f, 0.f, 0.f};
        if (r0 + r < NN)
            v = *reinterpret_cast<const float4*>(&x[(size_t)(r0 + r) * FIN + c4 * 4]);
        int base = r * LSTR + c4 * 4;
        xhi[base + 0] = f2bf(v.x);
        xhi[base + 1] = f2bf(v.y);
        xhi[base + 2] = f2bf(v.z);
        xhi[base + 3] = f2bf(v.w);
    }
    for (int i = t; i < 64 * 28; i += 256) {        // zero-pad k = 100..127
        int r = i / 28, c = FIN + (i - (i / 28) * 28);
        xhi[r * LSTR + c] = 0;
    }
    __syncthreads();
    int wave = t >> 6, lane = t & 63;
    int lrow = wave * 16 + (lane & 15);
    bf16x8 ahi[4];
    #pragma unroll
    for (int ks = 0; ks < 4; ++ks) {
        int off = lrow * LSTR + ks * 32 + (lane >> 4) * 8;
        ahi[ks] = *reinterpret_cast<const bf16x8*>(&xhi[off]);
    }
    float bv[4];
    #pragma unroll
    for (int ct = 0; ct < 4; ++ct) bv[ct] = b[ct * 16 + (lane & 15)];
    int r = r0 + wave * 16;
    f32x4 acc[4];
    #pragma unroll
    for (int ct = 0; ct < 4; ++ct) {
        acc[ct] = {bv[ct], bv[ct], bv[ct], bv[ct]};
        #pragma unroll
        for (int ks = 0; ks < 4; ++ks) {
            int base = ((ct * 4 + ks) * 2) * 512 + lane * 8;
            bf16x8 wh = *reinterpret_cast<const bf16x8*>(&wf[base]);
            bf16x8 wl = *reinterpret_cast<const bf16x8*>(&wf[base + 512]);
            acc[ct] = __builtin_amdgcn_mfma_f32_16x16x32_bf16(ahi[ks], wh, acc[ct], 0, 0, 0);
            acc[ct] = __builtin_amdgcn_mfma_f32_16x16x32_bf16(ahi[ks], wl, acc[ct], 0, 0, 0);
        }
    }
    #pragma unroll
    for (int ct = 0; ct < 4; ++ct) {
        int ocol = ct * 16 + (lane & 15);
        #pragma unroll
        for (int i = 0; i < 4; ++i) {
            int orow = r + (lane >> 4) * 4 + i;
            if (orow < NN) out[orow * D + ocol] = f2bf(fmaxf(acc[ct][i], 0.f));
        }
    }
}

// ---------------- FUSED conv, wave-private tiles: no block barriers -----------
// block = 256 (4 waves); each wave owns 16 nodes: 4 gather passes of 4 nodes
// (g = lane>>4 node, f = lane&15 feature-quad, 4-deep csr prefetch), rows
// staged bf16 in the wave's LDS tile, then the wave's own 16-row MFMA.
__global__ __launch_bounds__(256, 8) void k_conv_fused(const ushort* __restrict__ src,
                                                       const int* __restrict__ rowstart,
                                                       const int2* __restrict__ csr,
                                                       const ushort* __restrict__ wf,
                                                       const float* __restrict__ bias,
                                                       ushort* __restrict__ dst) {
    __shared__ ushort arow[4][16 * ASTR];   // 9.2 KB total
    int t = threadIdx.x;
    int wave = t >> 6, lane = t & 63;
    int g = lane >> 4;          // node sub-index within pass
    int f = lane & 15;          // feature quad
    int n0 = blockIdx.x * 64 + wave * 16;
    if (n0 >= NN) return;       // whole-wave early exit (NN % 16 == 0)
    ushort* tile = arow[wave];

    #pragma unroll
    for (int p = 0; p < 4; ++p) {
        int rloc = p * 4 + g;
        int node = n0 + rloc;
        int e0 = rowstart[node], e1 = rowstart[node + 1];
        float4 acc = {0.f, 0.f, 0.f, 0.f};
        int2 p0, p1, p2, p3;
        {
            int a0 = e0 + 0 < e1 ? e0 + 0 : 0;
            int a1 = e0 + 1 < e1 ? e0 + 1 : 0;
            int a2 = e0 + 2 < e1 ? e0 + 2 : 0;
            int a3 = e0 + 3 < e1 ? e0 + 3 : 0;
            p0 = csr[a0]; p1 = csr[a1]; p2 = csr[a2]; p3 = csr[a3];
        }
        for (int base = e0; base < e1; base += 4) {
            int n0e = base + 4 < e1 ? base + 4 : 0;
            int n1e = base + 5 < e1 ? base + 5 : 0;
            int n2e = base + 6 < e1 ? base + 6 : 0;
            int n3e = base + 7 < e1 ? base + 7 : 0;
            int2 q0 = csr[n0e], q1 = csr[n1e], q2 = csr[n2e], q3 = csr[n3e];
            float w0 = (base + 0 < e1) ? __int_as_float(p0.y) : 0.f;
            float w1 = (base + 1 < e1) ? __int_as_float(p1.y) : 0.f;
            float w2 = (base + 2 < e1) ? __int_as_float(p2.y) : 0.f;
            float w3 = (base + 3 < e1) ? __int_as_float(p3.y) : 0.f;
            uint2 v0 = *reinterpret_cast<const uint2*>(&src[p0.x * D + f * 4]);
            uint2 v1 = *reinterpret_cast<const uint2*>(&src[p1.x * D + f * 4]);
            uint2 v2 = *reinterpret_cast<const uint2*>(&src[p2.x * D + f * 4]);
            uint2 v3 = *reinterpret_cast<const uint2*>(&src[p3.x * D + f * 4]);
            acc.x = fmaf(bflo(v0.x), w0, acc.x); acc.y = fmaf(bfhi(v0.x), w0, acc.y);
            acc.z = fmaf(bflo(v0.y), w0, acc.z); acc.w = fmaf(bfhi(v0.y), w0, acc.w);
            acc.x = fmaf(bflo(v1.x), w1, acc.x); acc.y = fmaf(bfhi(v1.x), w1, acc.y);
            acc.z = fmaf(bflo(v1.y), w1, acc.z); acc.w = fmaf(bfhi(v1.y), w1, acc.w);
            acc.x = fmaf(bflo(v2.x), w2, acc.x); acc.y = fmaf(bfhi(v2.x), w2, acc.y);
            acc.z = fmaf(bflo(v2.y), w2, acc.z); acc.w = fmaf(bfhi(v2.y), w2, acc.w);
            acc.x = fmaf(bflo(v3.x), w3, acc.x); acc.y = fmaf(bfhi(v3.x), w3, acc.y);
            acc.z = fmaf(bflo(v3.y), w3, acc.z); acc.w = fmaf(bfhi(v3.y), w3, acc.w);
            p0 = q0; p1 = q1; p2 = q2; p3 = q3;
        }
        uint2 o;
        o.x = (uint)f2bf(acc.x) | ((uint)f2bf(acc.y) << 16);
        o.y = (uint)f2bf(acc.z) | ((uint)f2bf(acc.w) << 16);
        *reinterpret_cast<uint2*>(&tile[rloc * ASTR + f * 4]) = o;
    }
    // wave-private MFMA: 16 rows x 64 cols (intra-wave LDS dep, no barrier)
    int arow_idx = lane & 15;
    bf16x8 a0 = *reinterpret_cast<const bf16x8*>(&tile[arow_idx * ASTR + (lane >> 4) * 8]);
    bf16x8 a1 = *reinterpret_cast<const bf16x8*>(&tile[arow_idx * ASTR + 32 + (lane >> 4) * 8]);
    #pragma unroll
    for (int ct = 0; ct < 4; ++ct) {
        int base0 = ((ct * 2 + 0) * 2) * 512 + lane * 8;
        int base1 = ((ct * 2 + 1) * 2) * 512 + lane * 8;
        bf16x8 wh0 = *reinterpret_cast<const bf16x8*>(&wf[base0]);
        bf16x8 wl0 = *reinterpret_cast<const bf16x8*>(&wf[base0 + 512]);
        bf16x8 wh1 = *reinterpret_cast<const bf16x8*>(&wf[base1]);
        bf16x8 wl1 = *reinterpret_cast<const bf16x8*>(&wf[base1 + 512]);
        float bv = bias[ct * 16 + (lane & 15)];
        f32x4 c = {bv, bv, bv, bv};
        c = __builtin_amdgcn_mfma_f32_16x16x32_bf16(a0, wh0, c, 0, 0, 0);
        c = __builtin_amdgcn_mfma_f32_16x16x32_bf16(a1, wh1, c, 0, 0, 0);
        c = __builtin_amdgcn_mfma_f32_16x16x32_bf16(a0, wl0, c, 0, 0, 0);
        c = __builtin_amdgcn_mfma_f32_16x16x32_bf16(a1, wl1, c, 0, 0, 0);
        int ocol = ct * 16 + (lane & 15);
        #pragma unroll
        for (int i = 0; i < 4; ++i) {
            int orow = n0 + (lane >> 4) * 4 + i;
            dst[orow * D + ocol] = f2bf(fmaxf(c[i], 0.f));
        }
    }
}

// ---------------- segmented mean-pool over sorted batch (bf16 src) ------------
__global__ __launch_bounds__(256) void k_pool(const ushort* __restrict__ src,
                                              const int* __restrict__ batch,
                                              float* __restrict__ pooled,
                                              float* __restrict__ cnt) {
    int wave = threadIdx.x >> 6, lane = threadIdx.x & 63;
    int n0 = blockIdx.x * 64 + wave * 16;
    float s = 0.f;
    int curg = -1, runlen = 0;
    for (int i = 0; i < 16; ++i) {
        int node = n0 + i;
        if (node >= NN) break;
        int gg = batch[node];
        if (gg != curg) {
            if (curg >= 0) {
                atomicAdd(&pooled[curg * D + lane], s);
                if (lane == 0) atomicAdd(&cnt[curg], (float)runlen);
            }
            curg = gg; s = 0.f; runlen = 0;
        }
        s += bf2f(src[node * D + lane]);
        ++runlen;
    }
    if (curg >= 0) {
        atomicAdd(&pooled[curg * D + lane], s);
        if (lane == 0) atomicAdd(&cnt[curg], (float)runlen);
    }
}

// ---------------- MLP head: one block per graph ----------------
__global__ __launch_bounds__(64) void k_head(const float* __restrict__ pooled,
                                             const float* __restrict__ cnt,
                                             const float* __restrict__ lin1_w,
                                             const float* __restrict__ lin1_b,
                                             const float* __restrict__ fc_w,
                                             const float* __restrict__ fc_b,
                                             const float* __restrict__ lin2_w,
                                             const float* __restrict__ lin2_b,
                                             float* __restrict__ out) {
    __shared__ float buf0[D], buf1[D];
    int g = blockIdx.x, d = threadIdx.x;
    float c = fmaxf(cnt[g], 1.0f);
    buf0[d] = pooled[g * D + d] / c;
    __syncthreads();
    float acc = lin1_b[d];
    #pragma unroll
    for (int k = 0; k < D; ++k) acc += buf0[k] * lin1_w[k * D + d];
    buf1[d] = fmaxf(acc, 0.f);
    __syncthreads();
    acc = fc_b[d];
    #pragma unroll
    for (int k = 0; k < D; ++k) acc += buf1[k] * fc_w[k * D + d];
    buf0[d] = fmaxf(acc, 0.f);
    __syncthreads();
    acc = fc_b[D + d];
    #pragma unroll
    for (int k = 0; k < D; ++k) acc += buf0[k] * fc_w[D * D + k * D + d];
    buf1[d] = fmaxf(acc, 0.f);
    __syncthreads();
    float v = buf1[d] * lin2_w[d];
    #pragma unroll
    for (int off = 32; off; off >>= 1) v += __shfl_down(v, off);
    if (d == 0) out[g] = v + lin2_b[0];
}

extern "C" void kernel_launch(void* const* d_in, const int* in_sizes, int n_in,
                              void* d_out, int out_size, void* d_ws, size_t ws_size,
                              hipStream_t stream) {
    const float* x      = (const float*)d_in[0];
    const int*   ei     = (const int*)  d_in[1];
    const float* ew     = (const float*)d_in[2];
    const int*   batch  = (const int*)  d_in[3];
    const float* lin0_w = (const float*)d_in[4];
    const float* lin0_b = (const float*)d_in[5];
    const float* conv_w = (const float*)d_in[6];
    const float* conv_b = (const float*)d_in[7];
    const float* lin1_w = (const float*)d_in[8];
    const float* lin1_b = (const float*)d_in[9];
    const float* fc_w   = (const float*)d_in[10];
    const float* fc_b   = (const float*)d_in[11];
    const float* lin2_w = (const float*)d_in[12];
    const float* lin2_b = (const float*)d_in[13];
    float* out = (float*)d_out;

    const int* rowv = ei;
    const int* colv = ei + NE;

    // workspace layout (~53 MB)
    ushort* bufA    = (ushort*)d_ws;                  // N*D bf16 (12.8 MB)
    ushort* bufB    = bufA + (size_t)NN * D;          // N*D bf16
    ushort* bufG    = bufB + (size_t)NN * D;          // N*D bf16 (build scratch)
    int2*   csr     = (int2*)(bufG + (size_t)NN * D); // E (src, weight-bits)
    int*   rowstart = (int*)(csr + NE);               // N+1
    float* dis      = (float*)(rowstart + NN + 1);    // N
    float* pooled   = dis + NN;                       // G*D
    float* cnt      = pooled + NG * D;                // G
    ushort* wfrags  = (ushort*)(cnt + NG);            // 4*8192 bf16 = 64 KB
    ushort* wfrags0 = wfrags + 4 * 8192;              // 8192*2 bf16 = 32 KB
    // build-phase overlays (dead regions during build):
    int2*  sorted   = (int2*)bufG;                    // E * 8B == N*D*2B exactly
    int*   ghist    = (int*)bufB;                     // NSCAN ints
    int*   gscan    = ghist + NSCAN;                  // NSCAN ints
    int*   bsums    = gscan + NSCAN;                  // NBLKS ints

    hipMemsetAsync(pooled, 0, (NG * D + NG) * sizeof(float), stream);

    // ---- atomic-free CSR build (LDS multisplit counting sort) ----
    k_hist<<<NBLKA, 256, 0, stream>>>(colv, ghist);
    s_scan1<<<NBLKS, SB, 0, stream>>>(ghist, gscan, bsums, NSCAN);
    s_scan2<<<1, SB, 0, stream>>>(bsums, NBLKS);
    s_scan3<<<NBLKS, SB, 0, stream>>>(gscan, bsums, NSCAN);
    k_scatter<<<NBLKA, 256, 0, stream>>>(rowv, colv, ew, gscan, sorted);
    k_bcsr<<<NB, SB, 0, stream>>>(sorted, gscan, rowstart, csr, dis);

    k_rownorm<<<NN / 16, 256, 0, stream>>>(csr, rowstart, dis);
    k_wsplit_all<<<96, 256, 0, stream>>>(conv_w, lin0_w, wfrags, wfrags0);

    k_lin0_mfma<<<(NN + 63) / 64, 256, 0, stream>>>(x, wfrags0, lin0_b, bufA);

    int cg = (NN + 63) / 64;
    k_conv_fused<<<cg, 256, 0, stream>>>(bufA, rowstart, csr, wfrags + 0 * 8192,
                                         conv_b + 0 * D, bufB);
    k_conv_fused<<<cg, 256, 0, stream>>>(bufB, rowstart, csr, wfrags + 1 * 8192,
                                         conv_b + 1 * D, bufA);
    k_conv_fused<<<cg, 256, 0, stream>>>(bufA, rowstart, csr, wfrags + 2 * 8192,
                                         conv_b + 2 * D, bufB);
    k_conv_fused<<<cg, 256, 0, stream>>>(bufB, rowstart, csr, wfrags + 3 * 8192,
                                         conv_b + 3 * D, bufA);

    k_pool<<<(NN + 63) / 64, 256, 0, stream>>>(bufA, batch, pooled, cnt);
    k_head<<<NG, 64, 0, stream>>>(pooled, cnt, lin1_w, lin1_b, fc_w, fc_b,
                                  lin2_w, lin2_b, out);
}

// Round 13
// 280.952 us; speedup vs baseline: 1.1070x; 1.1070x over previous
//
#include <hip/hip_runtime.h>

#define NN 100000     // nodes
#define NE 1600000    // edges
#define FIN 100
#define D 64
#define NCONV 4
#define NG 500

// ---- bucket-sort CSR build params ----
#define NB 196                          // coarse buckets (col >> 9)
#define BSH 9
#define EPB 4096                        // edges per block in hist/scatter
#define NBLKA ((NE + EPB - 1) / EPB)    // 391
#define NSCAN (NB * NBLKA)              // 76636
#define SB 512                          // scan / bcsr block size
#define NBLKS ((NSCAN + SB - 1) / SB)   // 150

#define LSTR 136                        // LDS row stride (bf16) for lin0 staging
#define ASTR 72                         // LDS row stride (ushort) for fused conv tile

typedef unsigned int uint;
typedef unsigned short ushort;
typedef __attribute__((ext_vector_type(8))) short bf16x8;
typedef __attribute__((ext_vector_type(4))) float f32x4;

// f32 -> bf16 round-to-nearest-even
__device__ inline ushort f2bf(float x) {
    uint u = __float_as_uint(x);
    u += 0x7fffu + ((u >> 16) & 1u);
    return (ushort)(u >> 16);
}
__device__ inline float bflo(uint u) { return __uint_as_float(u << 16); }
__device__ inline float bfhi(uint u) { return __uint_as_float(u & 0xffff0000u); }
__device__ inline float bf2f(ushort s) { return __uint_as_float((uint)s << 16); }

// ---------------- pass A1: per-block LDS histogram over 196 buckets ----------
__global__ __launch_bounds__(256) void k_hist(const int* __restrict__ col,
                                              int* __restrict__ ghist) {
    __shared__ int lh[NB];
    int t = threadIdx.x;
    if (t < NB) lh[t] = 0;
    __syncthreads();
    int base = blockIdx.x * EPB;
    #pragma unroll
    for (int i = 0; i < 16; ++i) {
        int e = base + i * 256 + t;
        if (e < NE) atomicAdd(&lh[col[e] >> BSH], 1);
    }
    __syncthreads();
    if (t < NB) ghist[t * NBLKA + blockIdx.x] = lh[t];
}

// ---------------- generic two-level exclusive scan ----------------
__global__ __launch_bounds__(SB) void s_scan1(const int* __restrict__ in,
                                              int* __restrict__ out,
                                              int* __restrict__ bsums, int n) {
    __shared__ int sh[SB];
    int t = threadIdx.x, i = blockIdx.x * SB + t;
    int v = (i < n) ? in[i] : 0;
    sh[t] = v;
    __syncthreads();
    for (int off = 1; off < SB; off <<= 1) {
        int u = (t >= off) ? sh[t - off] : 0;
        __syncthreads();
        sh[t] += u;
        __syncthreads();
    }
    if (i < n) out[i] = sh[t] - v;
    if (t == SB - 1) bsums[blockIdx.x] = sh[t];
}

__global__ __launch_bounds__(SB) void s_scan2(int* __restrict__ bsums, int nb) {
    __shared__ int sh[SB];
    int t = threadIdx.x;
    int v = (t < nb) ? bsums[t] : 0;
    sh[t] = v;
    __syncthreads();
    for (int off = 1; off < SB; off <<= 1) {
        int u = (t >= off) ? sh[t - off] : 0;
        __syncthreads();
        sh[t] += u;
        __syncthreads();
    }
    if (t < nb) bsums[t] = sh[t] - v;
}

__global__ __launch_bounds__(SB) void s_scan3(int* __restrict__ out,
                                              const int* __restrict__ bsums, int n) {
    int i = blockIdx.x * SB + threadIdx.x;
    if (i < n) out[i] += bsums[blockIdx.x];
}

// ---------------- pass A3: scatter edges into bucket-sorted order -------------
__global__ __launch_bounds__(256) void k_scatter(const int* __restrict__ row,
                                                 const int* __restrict__ col,
                                                 const float* __restrict__ ew,
                                                 const int* __restrict__ gscan,
                                                 int2* __restrict__ sorted) {
    __shared__ int lcur[NB];
    int t = threadIdx.x;
    if (t < NB) lcur[t] = gscan[t * NBLKA + blockIdx.x];
    __syncthreads();
    int base = blockIdx.x * EPB;
    #pragma unroll
    for (int i = 0; i < 16; ++i) {
        int e = base + i * 256 + t;
        if (e < NE) {
            int c = col[e];
            int pos = atomicAdd(&lcur[c >> BSH], 1);
            sorted[pos] = make_int2(row[e] | ((c & 511) << 17), __float_as_int(ew[e]));
        }
    }
}

// ---------------- pass B: per-bucket fine CSR + degree (fused) ----------------
__global__ __launch_bounds__(SB) void k_bcsr(const int2* __restrict__ sorted,
                                             const int* __restrict__ gscan,
                                             int* __restrict__ rowstart,
                                             int2* __restrict__ csr,
                                             float* __restrict__ dis) {
    __shared__ int lcnt[SB];
    __shared__ int lscan[SB];
    __shared__ float ldeg[SB];
    int t = threadIdx.x, b = blockIdx.x;
    int base = gscan[b * NBLKA];
    int end  = (b == NB - 1) ? NE : gscan[(b + 1) * NBLKA];
    lcnt[t] = 0;
    ldeg[t] = 0.f;
    __syncthreads();
    for (int e = base + t; e < end; e += SB) {
        int2 p = sorted[e];
        int c = p.x >> 17;
        atomicAdd(&lcnt[c], 1);
        atomicAdd(&ldeg[c], __int_as_float(p.y));
    }
    __syncthreads();
    int v = lcnt[t];
    lscan[t] = v;
    __syncthreads();
    for (int off = 1; off < SB; off <<= 1) {
        int u = (t >= off) ? lscan[t - off] : 0;
        __syncthreads();
        lscan[t] += u;
        __syncthreads();
    }
    int ex = lscan[t] - v;           // exclusive scan within bucket
    int idx = b * SB + t;
    if (idx <= NN) rowstart[idx] = base + ex;
    if (idx < NN) {
        float dd = ldeg[t];
        dis[idx] = (dd > 0.f) ? (1.0f / sqrtf(dd)) : 0.f;
    }
    lcnt[t] = base + ex;             // cursor
    __syncthreads();
    for (int e = base + t; e < end; e += SB) {
        int2 p = sorted[e];
        int slot = atomicAdd(&lcnt[p.x >> 17], 1);
        csr[slot] = make_int2(p.x & 0x1FFFF, p.y);
    }
}

// ---------------- csr weight: ew -> dis[src]*ew*dis[dst], coalesced -----------
__global__ __launch_bounds__(256) void k_rownorm(int2* __restrict__ csr,
                                                 const int* __restrict__ rowstart,
                                                 const float* __restrict__ dis) {
    int t = threadIdx.x;
    int node = blockIdx.x * 16 + (t >> 4);
    int f = t & 15;
    int e0 = rowstart[node], e1 = rowstart[node + 1];
    float dc = dis[node];
    for (int e = e0 + f; e < e1; e += 16) {
        int2 p = csr[e];
        float w = dis[p.x] * __int_as_float(p.y) * dc;
        csr[e] = make_int2(p.x, __float_as_int(w));
    }
}

// ---------------- fused weight split (conv layers + lin0), pre-swizzled -------
__global__ void k_wsplit_all(const float* __restrict__ conv_w,
                             const float* __restrict__ lin0_w,
                             ushort* __restrict__ wf, ushort* __restrict__ wf0) {
    int tid = blockIdx.x * blockDim.x + threadIdx.x;   // 16384 + 8192 = 24576
    if (tid < 16384) {
        int j = tid & 7;
        int lane = (tid >> 3) & 63;
        int kh = (tid >> 9) & 1;
        int ct = (tid >> 10) & 3;
        int l = tid >> 12;
        int k = kh * 32 + (lane >> 4) * 8 + j;
        int n = ct * 16 + (lane & 15);
        float w = conv_w[l * D * D + k * D + n];
        ushort hi = f2bf(w);
        ushort lo = f2bf(w - bf2f(hi));
        int base = (((l * 4 + ct) * 2 + kh) * 2) * 512 + lane * 8 + j;
        wf[base] = hi;
        wf[base + 512] = lo;
    } else {
        int s = tid - 16384;
        int j = s & 7;
        int lane = (s >> 3) & 63;
        int ks = (s >> 9) & 3;
        int ct = s >> 11;
        int k = ks * 32 + (lane >> 4) * 8 + j;
        int n = ct * 16 + (lane & 15);
        float v = (k < FIN) ? lin0_w[k * D + n] : 0.f;
        ushort hi = f2bf(v);
        ushort lo = f2bf(v - bf2f(hi));
        int base = ((ct * 4 + ks) * 2) * 512 + lane * 8 + j;
        wf0[base] = hi;
        wf0[base + 512] = lo;
    }
}

// ---------------- lin0 via MFMA: out = relu(xhi @ (Whi+Wlo) + b0) -> bf16 -----
__global__ __launch_bounds__(256) void k_lin0_mfma(const float* __restrict__ x,
                                                   const ushort* __restrict__ wf,
                                                   const float* __restrict__ b,
                                                   ushort* __restrict__ out) {
    __shared__ ushort xhi[64 * LSTR];   // 17.4 KB
    int t = threadIdx.x;
    int r0 = blockIdx.x * 64;
    for (int i = t; i < 1600; i += 256) {           // 64 rows x 25 float4
        int r = i / 25, c4 = i - (i / 25) * 25;
        float4 v = {0.f, 0.f, 0.f, 0.f};
        if (r0 + r < NN)
            v = *reinterpret_cast<const float4*>(&x[(size_t)(r0 + r) * FIN + c4 * 4]);
        int base = r * LSTR + c4 * 4;
        xhi[base + 0] = f2bf(v.x);
        xhi[base + 1] = f2bf(v.y);
        xhi[base + 2] = f2bf(v.z);
        xhi[base + 3] = f2bf(v.w);
    }
    for (int i = t; i < 64 * 28; i += 256) {        // zero-pad k = 100..127
        int r = i / 28, c = FIN + (i - (i / 28) * 28);
        xhi[r * LSTR + c] = 0;
    }
    __syncthreads();
    int wave = t >> 6, lane = t & 63;
    int lrow = wave * 16 + (lane & 15);
    bf16x8 ahi[4];
    #pragma unroll
    for (int ks = 0; ks < 4; ++ks) {
        int off = lrow * LSTR + ks * 32 + (lane >> 4) * 8;
        ahi[ks] = *reinterpret_cast<const bf16x8*>(&xhi[off]);
    }
    float bv[4];
    #pragma unroll
    for (int ct = 0; ct < 4; ++ct) bv[ct] = b[ct * 16 + (lane & 15)];
    int r = r0 + wave * 16;
    f32x4 acc[4];
    #pragma unroll
    for (int ct = 0; ct < 4; ++ct) {
        acc[ct] = {bv[ct], bv[ct], bv[ct], bv[ct]};
        #pragma unroll
        for (int ks = 0; ks < 4; ++ks) {
            int base = ((ct * 4 + ks) * 2) * 512 + lane * 8;
            bf16x8 wh = *reinterpret_cast<const bf16x8*>(&wf[base]);
            bf16x8 wl = *reinterpret_cast<const bf16x8*>(&wf[base + 512]);
            acc[ct] = __builtin_amdgcn_mfma_f32_16x16x32_bf16(ahi[ks], wh, acc[ct], 0, 0, 0);
            acc[ct] = __builtin_amdgcn_mfma_f32_16x16x32_bf16(ahi[ks], wl, acc[ct], 0, 0, 0);
        }
    }
    #pragma unroll
    for (int ct = 0; ct < 4; ++ct) {
        int ocol = ct * 16 + (lane & 15);
        #pragma unroll
        for (int i = 0; i < 4; ++i) {
            int orow = r + (lane >> 4) * 4 + i;
            if (orow < NN) out[orow * D + ocol] = f2bf(fmaxf(acc[ct][i], 0.f));
        }
    }
}

// ---------------- FUSED conv (R11 structure): 16 nodes/block, 4 waves x 4 nodes
// gather with 4-deep csr prefetch -> LDS bf16 tile -> barrier -> wave w does
// col-tile ct=w of the 16-row MFMA.
__global__ __launch_bounds__(256, 8) void k_conv_fused(const ushort* __restrict__ src,
                                                       const int* __restrict__ rowstart,
                                                       const int2* __restrict__ csr,
                                                       const ushort* __restrict__ wf,
                                                       const float* __restrict__ bias,
                                                       ushort* __restrict__ dst) {
    __shared__ ushort arow[16 * ASTR];   // 2.3 KB
    int t = threadIdx.x;
    int wave = t >> 6, lane = t & 63;
    int g = lane >> 4;          // node sub-index within wave
    int f = lane & 15;          // feature quad
    int rloc = wave * 4 + g;    // local row 0..15
    int node = blockIdx.x * 16 + rloc;   // NN % 16 == 0
    int e0 = rowstart[node], e1 = rowstart[node + 1];
    float4 acc = {0.f, 0.f, 0.f, 0.f};
    int2 p0, p1, p2, p3;
    {
        int a0 = e0 + 0 < e1 ? e0 + 0 : 0;
        int a1 = e0 + 1 < e1 ? e0 + 1 : 0;
        int a2 = e0 + 2 < e1 ? e0 + 2 : 0;
        int a3 = e0 + 3 < e1 ? e0 + 3 : 0;
        p0 = csr[a0]; p1 = csr[a1]; p2 = csr[a2]; p3 = csr[a3];
    }
    for (int base = e0; base < e1; base += 4) {
        int n0 = base + 4 < e1 ? base + 4 : 0;
        int n1 = base + 5 < e1 ? base + 5 : 0;
        int n2 = base + 6 < e1 ? base + 6 : 0;
        int n3 = base + 7 < e1 ? base + 7 : 0;
        int2 q0 = csr[n0], q1 = csr[n1], q2 = csr[n2], q3 = csr[n3];
        float w0 = (base + 0 < e1) ? __int_as_float(p0.y) : 0.f;
        float w1 = (base + 1 < e1) ? __int_as_float(p1.y) : 0.f;
        float w2 = (base + 2 < e1) ? __int_as_float(p2.y) : 0.f;
        float w3 = (base + 3 < e1) ? __int_as_float(p3.y) : 0.f;
        uint2 v0 = *reinterpret_cast<const uint2*>(&src[p0.x * D + f * 4]);
        uint2 v1 = *reinterpret_cast<const uint2*>(&src[p1.x * D + f * 4]);
        uint2 v2 = *reinterpret_cast<const uint2*>(&src[p2.x * D + f * 4]);
        uint2 v3 = *reinterpret_cast<const uint2*>(&src[p3.x * D + f * 4]);
        acc.x = fmaf(bflo(v0.x), w0, acc.x); acc.y = fmaf(bfhi(v0.x), w0, acc.y);
        acc.z = fmaf(bflo(v0.y), w0, acc.z); acc.w = fmaf(bfhi(v0.y), w0, acc.w);
        acc.x = fmaf(bflo(v1.x), w1, acc.x); acc.y = fmaf(bfhi(v1.x), w1, acc.y);
        acc.z = fmaf(bflo(v1.y), w1, acc.z); acc.w = fmaf(bfhi(v1.y), w1, acc.w);
        acc.x = fmaf(bflo(v2.x), w2, acc.x); acc.y = fmaf(bfhi(v2.x), w2, acc.y);
        acc.z = fmaf(bflo(v2.y), w2, acc.z); acc.w = fmaf(bfhi(v2.y), w2, acc.w);
        acc.x = fmaf(bflo(v3.x), w3, acc.x); acc.y = fmaf(bfhi(v3.x), w3, acc.y);
        acc.z = fmaf(bflo(v3.y), w3, acc.z); acc.w = fmaf(bfhi(v3.y), w3, acc.w);
        p0 = q0; p1 = q1; p2 = q2; p3 = q3;
    }
    // stage aggregated row (bf16) into LDS tile
    uint2 o;
    o.x = (uint)f2bf(acc.x) | ((uint)f2bf(acc.y) << 16);
    o.y = (uint)f2bf(acc.z) | ((uint)f2bf(acc.w) << 16);
    *reinterpret_cast<uint2*>(&arow[rloc * ASTR + f * 4]) = o;
    __syncthreads();
    // MFMA tail: wave computes col-tile ct = wave
    int ct = wave;
    int base0 = ((ct * 2 + 0) * 2) * 512 + lane * 8;   // kh=0
    int base1 = ((ct * 2 + 1) * 2) * 512 + lane * 8;   // kh=1
    bf16x8 wh0 = *reinterpret_cast<const bf16x8*>(&wf[base0]);
    bf16x8 wl0 = *reinterpret_cast<const bf16x8*>(&wf[base0 + 512]);
    bf16x8 wh1 = *reinterpret_cast<const bf16x8*>(&wf[base1]);
    bf16x8 wl1 = *reinterpret_cast<const bf16x8*>(&wf[base1 + 512]);
    int arow_idx = lane & 15;
    bf16x8 a0 = *reinterpret_cast<const bf16x8*>(&arow[arow_idx * ASTR + (lane >> 4) * 8]);
    bf16x8 a1 = *reinterpret_cast<const bf16x8*>(&arow[arow_idx * ASTR + 32 + (lane >> 4) * 8]);
    float bv = bias[ct * 16 + (lane & 15)];
    f32x4 c = {bv, bv, bv, bv};
    c = __builtin_amdgcn_mfma_f32_16x16x32_bf16(a0, wh0, c, 0, 0, 0);
    c = __builtin_amdgcn_mfma_f32_16x16x32_bf16(a1, wh1, c, 0, 0, 0);
    c = __builtin_amdgcn_mfma_f32_16x16x32_bf16(a0, wl0, c, 0, 0, 0);
    c = __builtin_amdgcn_mfma_f32_16x16x32_bf16(a1, wl1, c, 0, 0, 0);
    int ocol = ct * 16 + (lane & 15);
    int r0 = blockIdx.x * 16;
    #pragma unroll
    for (int i = 0; i < 4; ++i) {
        int orow = r0 + (lane >> 4) * 4 + i;
        dst[orow * D + ocol] = f2bf(fmaxf(c[i], 0.f));
    }
}

// ---------------- segmented mean-pool over sorted batch (bf16 src) ------------
__global__ __launch_bounds__(256) void k_pool(const ushort* __restrict__ src,
                                              const int* __restrict__ batch,
                                              float* __restrict__ pooled,
                                              float* __restrict__ cnt) {
    int wave = threadIdx.x >> 6, lane = threadIdx.x & 63;
    int n0 = blockIdx.x * 64 + wave * 16;
    float s = 0.f;
    int curg = -1, runlen = 0;
    for (int i = 0; i < 16; ++i) {
        int node = n0 + i;
        if (node >= NN) break;
        int gg = batch[node];
        if (gg != curg) {
            if (curg >= 0) {
                atomicAdd(&pooled[curg * D + lane], s);
                if (lane == 0) atomicAdd(&cnt[curg], (float)runlen);
            }
            curg = gg; s = 0.f; runlen = 0;
        }
        s += bf2f(src[node * D + lane]);
        ++runlen;
    }
    if (curg >= 0) {
        atomicAdd(&pooled[curg * D + lane], s);
        if (lane == 0) atomicAdd(&cnt[curg], (float)runlen);
    }
}

// ---------------- MLP head: one block per graph ----------------
__global__ __launch_bounds__(64) void k_head(const float* __restrict__ pooled,
                                             const float* __restrict__ cnt,
                                             const float* __restrict__ lin1_w,
                                             const float* __restrict__ lin1_b,
                                             const float* __restrict__ fc_w,
                                             const float* __restrict__ fc_b,
                                             const float* __restrict__ lin2_w,
                                             const float* __restrict__ lin2_b,
                                             float* __restrict__ out) {
    __shared__ float buf0[D], buf1[D];
    int g = blockIdx.x, d = threadIdx.x;
    float c = fmaxf(cnt[g], 1.0f);
    buf0[d] = pooled[g * D + d] / c;
    __syncthreads();
    float acc = lin1_b[d];
    #pragma unroll
    for (int k = 0; k < D; ++k) acc += buf0[k] * lin1_w[k * D + d];
    buf1[d] = fmaxf(acc, 0.f);
    __syncthreads();
    acc = fc_b[d];
    #pragma unroll
    for (int k = 0; k < D; ++k) acc += buf1[k] * fc_w[k * D + d];
    buf0[d] = fmaxf(acc, 0.f);
    __syncthreads();
    acc = fc_b[D + d];
    #pragma unroll
    for (int k = 0; k < D; ++k) acc += buf0[k] * fc_w[D * D + k * D + d];
    buf1[d] = fmaxf(acc, 0.f);
    __syncthreads();
    float v = buf1[d] * lin2_w[d];
    #pragma unroll
    for (int off = 32; off; off >>= 1) v += __shfl_down(v, off);
    if (d == 0) out[g] = v + lin2_b[0];
}

extern "C" void kernel_launch(void* const* d_in, const int* in_sizes, int n_in,
                              void* d_out, int out_size, void* d_ws, size_t ws_size,
                              hipStream_t stream) {
    const float* x      = (const float*)d_in[0];
    const int*   ei     = (const int*)  d_in[1];
    const float* ew     = (const float*)d_in[2];
    const int*   batch  = (const int*)  d_in[3];
    const float* lin0_w = (const float*)d_in[4];
    const float* lin0_b = (const float*)d_in[5];
    const float* conv_w = (const float*)d_in[6];
    const float* conv_b = (const float*)d_in[7];
    const float* lin1_w = (const float*)d_in[8];
    const float* lin1_b = (const float*)d_in[9];
    const float* fc_w   = (const float*)d_in[10];
    const float* fc_b   = (const float*)d_in[11];
    const float* lin2_w = (const float*)d_in[12];
    const float* lin2_b = (const float*)d_in[13];
    float* out = (float*)d_out;

    const int* rowv = ei;
    const int* colv = ei + NE;

    // workspace layout (~53 MB)
    ushort* bufA    = (ushort*)d_ws;                  // N*D bf16 (12.8 MB)
    ushort* bufB    = bufA + (size_t)NN * D;          // N*D bf16
    ushort* bufG    = bufB + (size_t)NN * D;          // N*D bf16 (build scratch)
    int2*   csr     = (int2*)(bufG + (size_t)NN * D); // E (src, weight-bits)
    int*   rowstart = (int*)(csr + NE);               // N+1
    float* dis      = (float*)(rowstart + NN + 1);    // N
    float* pooled   = dis + NN;                       // G*D
    float* cnt      = pooled + NG * D;                // G
    ushort* wfrags  = (ushort*)(cnt + NG);            // 4*8192 bf16 = 64 KB
    ushort* wfrags0 = wfrags + 4 * 8192;              // 8192*2 bf16 = 32 KB
    // build-phase overlays (dead regions during build):
    int2*  sorted   = (int2*)bufG;                    // E * 8B == N*D*2B exactly
    int*   ghist    = (int*)bufB;                     // NSCAN ints
    int*   gscan    = ghist + NSCAN;                  // NSCAN ints
    int*   bsums    = gscan + NSCAN;                  // NBLKS ints

    hipMemsetAsync(pooled, 0, (NG * D + NG) * sizeof(float), stream);

    // ---- atomic-free CSR build (LDS multisplit counting sort) ----
    k_hist<<<NBLKA, 256, 0, stream>>>(colv, ghist);
    s_scan1<<<NBLKS, SB, 0, stream>>>(ghist, gscan, bsums, NSCAN);
    s_scan2<<<1, SB, 0, stream>>>(bsums, NBLKS);
    s_scan3<<<NBLKS, SB, 0, stream>>>(gscan, bsums, NSCAN);
    k_scatter<<<NBLKA, 256, 0, stream>>>(rowv, colv, ew, gscan, sorted);
    k_bcsr<<<NB, SB, 0, stream>>>(sorted, gscan, rowstart, csr, dis);

    k_rownorm<<<NN / 16, 256, 0, stream>>>(csr, rowstart, dis);
    k_wsplit_all<<<96, 256, 0, stream>>>(conv_w, lin0_w, wfrags, wfrags0);

    k_lin0_mfma<<<(NN + 63) / 64, 256, 0, stream>>>(x, wfrags0, lin0_b, bufA);

    int cg = NN / 16;
    k_conv_fused<<<cg, 256, 0, stream>>>(bufA, rowstart, csr, wfrags + 0 * 8192,
                                         conv_b + 0 * D, bufB);
    k_conv_fused<<<cg, 256, 0, stream>>>(bufB, rowstart, csr, wfrags + 1 * 8192,
                                         conv_b + 1 * D, bufA);
    k_conv_fused<<<cg, 256, 0, stream>>>(bufA, rowstart, csr, wfrags + 2 * 8192,
                                         conv_b + 2 * D, bufB);
    k_conv_fused<<<cg, 256, 0, stream>>>(bufB, rowstart, csr, wfrags + 3 * 8192,
                                         conv_b + 3 * D, bufA);

    k_pool<<<(NN + 63) / 64, 256, 0, stream>>>(bufA, batch, pooled, cnt);
    k_head<<<NG, 64, 0, stream>>>(pooled, cnt, lin1_w, lin1_b, fc_w, fc_b,
                                  lin2_w, lin2_b, out);
}